// Round 4
// baseline (9460.976 us; speedup 1.0000x reference)
//
#include <hip/hip_runtime.h>
#include <hip/hip_bf16.h>
#include <math.h>

// ---------------- constants (fixed by setup_inputs) ----------------
constexpr int B   = 128;   // batch
constexpr int N1  = 32;    // agents (1 ego + 31 veh)
constexpr int HH  = 20;    // history steps (T-2)
constexpr int L   = 64;    // lanes
constexpr int PTS = 10;    // points per lane
constexpr int F   = 128;   // feature size
constexpr int LF  = 64;    // lane feature
constexpr int NH  = 8;     // heads
constexpr int HD  = 16;    // head dim
constexpr int KVN = 96;    // kv tokens = 32 agents + 64 lanes
constexpr int G4  = 512;   // 4*F lstm gates
constexpr int NP  = 6;     // num preds
constexpr int P6  = 36;    // NP*6
constexpr int LEN = 30;    // len_pred

__device__ __forceinline__ float sigmoidf(float x) { return 1.f / (1.f + expf(-x)); }

// ---------------- one-time kernels ----------------

// lane MLP -> lane tokens (kv rows 32..95). One wave per (b,l).
// All shared operands (lane_input, w1, b1) are wave-uniform -> scalar loads.
__global__ __launch_bounds__(64) void k_lane_tok(
        const float* __restrict__ lane_input,
        const float* __restrict__ w1, const float* __restrict__ b1,
        const float* __restrict__ w2, const float* __restrict__ b2,
        const float* __restrict__ to_f,
        float* __restrict__ kvbuf) {
    int bl = blockIdx.x; int b = bl / L, l = bl % L;
    int j = threadIdx.x; // 64
    float x0[PTS], x1[PTS];
#pragma unroll
    for (int p = 0; p < PTS; ++p) {
        x0[p] = lane_input[((size_t)(b * L + l) * PTS + p) * 2 + 0]; // uniform -> s_load
        x1[p] = lane_input[((size_t)(b * L + l) * PTS + p) * 2 + 1];
    }
    float mp[PTS];
#pragma unroll
    for (int p = 0; p < PTS; ++p) mp[p] = 0.f;
    for (int hh = 0; hh < LF; ++hh) {
        float w10 = w1[hh], w11 = w1[LF + hh], b1h = b1[hh]; // uniform
        float wv = w2[hh * LF + j];                          // per-lane, coalesced
#pragma unroll
        for (int p = 0; p < PTS; ++p) {
            float h1v = fmaxf(x0[p] * w10 + x1[p] * w11 + b1h, 0.f);
            mp[p] += h1v * wv;
        }
    }
    float b2j = b2[j];
    float m = 0.f;
#pragma unroll
    for (int p = 0; p < PTS; ++p) m += fmaxf(mp[p] + b2j, 0.f);
    m *= (1.f / PTS);
    __shared__ float ml[LF];
    ml[j] = m;
    __syncthreads();
    float* outp = kvbuf + ((size_t)(b * KVN) + 32 + l) * F;
    for (int f = j; f < F; f += LF) {
        float s = 0.f;
        for (int j2 = 0; j2 < LF; ++j2) s += ml[j2] * to_f[j2 * F + f];
        outp[f] = s;
    }
}

// lane K/V: project constant lane tokens once. 8 rows per block.
__global__ __launch_bounds__(256) void k_lane_kv(
        const float* __restrict__ kvbuf,
        const float* __restrict__ wk, const float* __restrict__ wv,
        float* __restrict__ kb, float* __restrict__ vb) {
    int g = blockIdx.x & 7, b = blockIdx.x >> 3;
    int n0 = 32 + g * 8;
    int tid = threadIdx.x; // 256
    int j = tid & 127, rh = tid >> 7; // rh 0..1
    int r0 = rh * 4;
    float ak[4] = {0, 0, 0, 0}, av[4] = {0, 0, 0, 0};
    for (int k2 = 0; k2 < F; k2 += 4) {
        float4 xv[4];
#pragma unroll
        for (int r = 0; r < 4; ++r)
            xv[r] = *(const float4*)(kvbuf + ((size_t)b * KVN + n0 + r0 + r) * F + k2); // uniform
#pragma unroll
        for (int q = 0; q < 4; ++q) {
            float wkv = wk[(k2 + q) * F + j], wvv = wv[(k2 + q) * F + j];
#pragma unroll
            for (int r = 0; r < 4; ++r) {
                const float* xf = (const float*)&xv[r];
                ak[r] += xf[q] * wkv; av[r] += xf[q] * wvv;
            }
        }
    }
#pragma unroll
    for (int r = 0; r < 4; ++r) {
        int n = n0 + r0 + r;
        kb[((size_t)b * KVN + n) * F + j] = ak[r];
        vb[((size_t)b * KVN + n) * F + j] = av[r];
    }
}

__global__ void k_hist_pos(const float* __restrict__ input,
                           const float* __restrict__ init_pos,
                           float* __restrict__ hist_pos,
                           float* __restrict__ pred_pos) {
    int idx = blockIdx.x * blockDim.x + threadIdx.x;
    if (idx >= B * N1) return;
    float px = init_pos[idx * 2], py = init_pos[idx * 2 + 1];
    int b = idx / N1, n = idx % N1;
    for (int t = 0; t < HH; ++t) {
        const float* ip = input + ((size_t)(t * B + b) * N1 + n) * 2;
        float dl = ip[0], yaw = ip[1];
        px += dl * cosf(yaw);
        py += dl * sinf(yaw);
        float* hp = hist_pos + ((size_t)(t * B + b) * N1 + n) * 2;
        hp[0] = px; hp[1] = py;
    }
#pragma unroll
    for (int p = 0; p < NP; ++p) {
        pred_pos[((size_t)idx * NP + p) * 2 + 0] = px;
        pred_pos[((size_t)idx * NP + p) * 2 + 1] = py;
    }
}

__global__ void k_transpose_all(const float* __restrict__ w0, const float* __restrict__ w1,
                                const float* __restrict__ w2, const float* __restrict__ w3,
                                float* __restrict__ wt) {
    int i = blockIdx.x * blockDim.x + threadIdx.x;
    if (i >= 4 * G4 * F) return;
    int m = i / (G4 * F), rem = i % (G4 * F);
    int j = rem / F, k2 = rem % F;
    const float* src = (m == 0) ? w0 : (m == 1) ? w1 : (m == 2) ? w2 : w3;
    wt[(size_t)m * G4 * F + (size_t)k2 * G4 + j] = src[rem];
}

// ---------------- per-step kernels ----------------

// Kernel A: build agent tokens + q/k/v projections. grid B*4, block 256, 8 rows/block.
__global__ __launch_bounds__(256) void k_tok_qkv(
        const float* __restrict__ input, const float* __restrict__ hist_pos,
        const float* __restrict__ h, const float* __restrict__ pred_pos,
        const float* __restrict__ conv_w, const float* __restrict__ conv_b,
        const float* __restrict__ pos_w, const float* __restrict__ pos_b,
        const float* __restrict__ wq, const float* __restrict__ wk,
        const float* __restrict__ wv,
        float* __restrict__ kvbuf, float* __restrict__ qb,
        float* __restrict__ kb, float* __restrict__ vb,
        int mode, int t) {
    int g = blockIdx.x & 3, b = blockIdx.x >> 2;
    int n0 = g * 8;
    int tid = threadIdx.x;
    int j = tid & 127, rh = tid >> 7;
    __shared__ float tok[8][F];
    for (int i = tid; i < 8 * F; i += 256) {
        int r = i >> 7, c = i & 127;
        int n = n0 + r;
        float acc;
        if (mode == 0) {
            acc = conv_b[c];
#pragma unroll
            for (int kt = 0; kt < 3; ++kt) {
                const float* ip = input + ((size_t)((t + kt) * B + b) * N1 + n) * 2;
                acc += ip[0] * conv_w[(c * 2 + 0) * 3 + kt] + ip[1] * conv_w[(c * 2 + 1) * 3 + kt];
            }
            const float* hp = hist_pos + ((size_t)(t * B + b) * N1 + n) * 2;
            acc += hp[0] * pos_w[c] + hp[1] * pos_w[F + c] + pos_b[c];
        } else {
            const float* pp = pred_pos + ((size_t)(b * N1 + n)) * NP * 2;
            float mx = 0.f, my = 0.f;
#pragma unroll
            for (int p = 0; p < NP; ++p) { mx += pp[p * 2]; my += pp[p * 2 + 1]; }
            mx *= (1.f / NP); my *= (1.f / NP);
            acc = h[((size_t)b * N1 + n) * F + c] + mx * pos_w[c] + my * pos_w[F + c] + pos_b[c];
        }
        tok[r][c] = acc;
        kvbuf[((size_t)b * KVN + n) * F + c] = acc;
    }
    __syncthreads();
    float aq[4] = {0, 0, 0, 0}, ak[4] = {0, 0, 0, 0}, av[4] = {0, 0, 0, 0};
    int r0 = rh * 4;
    for (int k2 = 0; k2 < F; k2 += 4) {
        float4 xv[4];
#pragma unroll
        for (int r = 0; r < 4; ++r) xv[r] = *(const float4*)&tok[r0 + r][k2]; // b128, broadcast
#pragma unroll
        for (int q = 0; q < 4; ++q) {
            float wqv = wq[(k2 + q) * F + j], wkv = wk[(k2 + q) * F + j], wvv = wv[(k2 + q) * F + j];
#pragma unroll
            for (int r = 0; r < 4; ++r) {
                const float* xf = (const float*)&xv[r];
                float x = xf[q];
                aq[r] += x * wqv; ak[r] += x * wkv; av[r] += x * wvv;
            }
        }
    }
#pragma unroll
    for (int r = 0; r < 4; ++r) {
        int n = n0 + r0 + r;
        qb[((size_t)b * N1 + n) * F + j]  = aq[r];
        kb[((size_t)b * KVN + n) * F + j] = ak[r];
        vb[((size_t)b * KVN + n) * F + j] = av[r];
    }
}

// Kernel B1: attention, online softmax entirely in registers. One wave per (b, 8 q-rows).
// lane = (qi, h): 8 q-rows x 8 heads. grid B*4, block 64. No LDS, no syncs.
__global__ __launch_bounds__(64) void k_attn(
        const float* __restrict__ qb, const float* __restrict__ kb,
        const float* __restrict__ vb,
        const float* __restrict__ mask_in, const float* __restrict__ lane_mask,
        float* __restrict__ ao) {
    int qg = blockIdx.x & 3, b = blockIdx.x >> 2;
    int t = threadIdx.x;
    int h = t & 7, qi = t >> 3;
    int qr = qg * 8 + qi;
    const float4* qp = (const float4*)(qb + ((size_t)b * N1 + qr) * F + h * HD);
    float4 q0 = qp[0], q1 = qp[1], q2 = qp[2], q3 = qp[3];
    float m = -1e30f, l = 0.f;
    float4 o0 = {0,0,0,0}, o1 = {0,0,0,0}, o2 = {0,0,0,0}, o3 = {0,0,0,0};
    const float4* kp = (const float4*)(kb + ((size_t)b * KVN) * F + h * HD);
    const float4* vp = (const float4*)(vb + ((size_t)b * KVN) * F + h * HD);
    for (int kc = 0; kc < KVN; ++kc) {
        float mval = (kc < N1) ? mask_in[b * N1 + kc] : lane_mask[b * L + (kc - N1)]; // uniform
        const float4* kk = kp + (size_t)kc * (F / 4);
        float4 k0 = kk[0], k1 = kk[1], k2v = kk[2], k3 = kk[3];
        float s = q0.x*k0.x + q0.y*k0.y + q0.z*k0.z + q0.w*k0.w
                + q1.x*k1.x + q1.y*k1.y + q1.z*k1.z + q1.w*k1.w
                + q2.x*k2v.x + q2.y*k2v.y + q2.z*k2v.z + q2.w*k2v.w
                + q3.x*k3.x + q3.y*k3.y + q3.z*k3.z + q3.w*k3.w;
        s = (mval > 0.f) ? s * 0.25f : -1e9f;
        float mn = fmaxf(m, s);
        float corr = expf(m - mn);
        float p = expf(s - mn);
        l = l * corr + p;
        const float4* vv = vp + (size_t)kc * (F / 4);
        float4 v0 = vv[0], v1 = vv[1], v2 = vv[2], v3 = vv[3];
        o0.x = o0.x*corr + p*v0.x; o0.y = o0.y*corr + p*v0.y; o0.z = o0.z*corr + p*v0.z; o0.w = o0.w*corr + p*v0.w;
        o1.x = o1.x*corr + p*v1.x; o1.y = o1.y*corr + p*v1.y; o1.z = o1.z*corr + p*v1.z; o1.w = o1.w*corr + p*v1.w;
        o2.x = o2.x*corr + p*v2.x; o2.y = o2.y*corr + p*v2.y; o2.z = o2.z*corr + p*v2.z; o2.w = o2.w*corr + p*v2.w;
        o3.x = o3.x*corr + p*v3.x; o3.y = o3.y*corr + p*v3.y; o3.z = o3.z*corr + p*v3.z; o3.w = o3.w*corr + p*v3.w;
        m = mn;
    }
    float inv = 1.f / l;
    o0.x *= inv; o0.y *= inv; o0.z *= inv; o0.w *= inv;
    o1.x *= inv; o1.y *= inv; o1.z *= inv; o1.w *= inv;
    o2.x *= inv; o2.y *= inv; o2.z *= inv; o2.w *= inv;
    o3.x *= inv; o3.y *= inv; o3.z *= inv; o3.w *= inv;
    float4* op = (float4*)(ao + ((size_t)b * N1 + qr) * F + h * HD);
    op[0] = o0; op[1] = o1; op[2] = o2; op[3] = o3;
}

// Kernel B2: out-proj + residual + layernorm. grid B*4, block 256, 8 rows/block.
// ao read with wave-uniform addresses -> scalar loads.
__global__ __launch_bounds__(256) void k_proj_ln(
        const float* __restrict__ ao, const float* __restrict__ kvbuf,
        const float* __restrict__ wo,
        const float* __restrict__ ln_ego_g, const float* __restrict__ ln_ego_b,
        const float* __restrict__ ln_g, const float* __restrict__ ln_b,
        float* __restrict__ xln) {
    int gq = blockIdx.x & 3, b = blockIdx.x >> 2;
    int n0 = gq * 8;
    int tid = threadIdx.x; // 256
    int j = tid & 127, rh = tid >> 7;
    int r0 = rh * 4;
    __shared__ float xb[8][F];
    __shared__ float st[8][2];
    float acc[4] = {0, 0, 0, 0};
    for (int k2 = 0; k2 < F; k2 += 4) {
        float4 av4[4];
#pragma unroll
        for (int r = 0; r < 4; ++r)
            av4[r] = *(const float4*)(ao + ((size_t)b * N1 + n0 + r0 + r) * F + k2); // uniform
#pragma unroll
        for (int q = 0; q < 4; ++q) {
            float w = wo[(k2 + q) * F + j];
#pragma unroll
            for (int r = 0; r < 4; ++r) {
                const float* af = (const float*)&av4[r];
                acc[r] += af[q] * w;
            }
        }
    }
#pragma unroll
    for (int r = 0; r < 4; ++r)
        xb[r0 + r][j] = kvbuf[((size_t)b * KVN + n0 + r0 + r) * F + j] + acc[r];
    __syncthreads();
    // LN stats: 8 rows x 32 segments, shuffle reduce within 32-lane segments
    {
        int row = tid >> 5, seg = tid & 31;
        float4 xv = *(const float4*)&xb[row][seg * 4];
        float s1 = xv.x + xv.y + xv.z + xv.w;
        float s2 = xv.x*xv.x + xv.y*xv.y + xv.z*xv.z + xv.w*xv.w;
#pragma unroll
        for (int off = 16; off > 0; off >>= 1) {
            s1 += __shfl_down(s1, off, 32);
            s2 += __shfl_down(s2, off, 32);
        }
        if (seg == 0) {
            float mean = s1 * (1.f / F);
            float var = s2 * (1.f / F) - mean * mean;
            st[row][0] = mean; st[row][1] = rsqrtf(var + 1e-5f);
        }
    }
    __syncthreads();
    for (int i = tid; i < 8 * F; i += 256) {
        int r = i >> 7, c = i & 127;
        int n = n0 + r;
        const float* g  = (n == 0) ? ln_ego_g : ln_g;
        const float* bb = (n == 0) ? ln_ego_b : ln_b;
        xln[((size_t)b * N1 + n) * F + c] = (xb[r][c] - st[r][0]) * st[r][1] * g[c] + bb[c];
    }
}

// Kernel C: LSTM cell (16 batch rows/block) + (pred mode) output head + pos update + y.
// x/h read via wave-uniform float4 loads (scalarizable: ping-pong buffers, never
// written in this dispatch). grid N1*8 = 256 blocks, block 512.
__global__ __launch_bounds__(512, 2) void k_lstm_pred(
        const float* __restrict__ xln,
        const float* __restrict__ ego_wih_t, const float* __restrict__ ego_whh_t,
        const float* __restrict__ ego_bih, const float* __restrict__ ego_bhh,
        const float* __restrict__ veh_wih_t, const float* __restrict__ veh_whh_t,
        const float* __restrict__ veh_bih, const float* __restrict__ veh_bhh,
        const float* __restrict__ h_in, const float* __restrict__ c_in,
        float* __restrict__ h_out, float* __restrict__ c_out,
        const float* __restrict__ out_ego_w, const float* __restrict__ out_ego_b,
        const float* __restrict__ out_w, const float* __restrict__ out_b,
        float* __restrict__ pred_pos, float* __restrict__ out,
        int mode, int step) {
    int n = blockIdx.x >> 3, bg = blockIdx.x & 7;
    int b0 = bg * 16;
    int j = threadIdx.x; // 512
    const float *wih, *whh, *bih, *bhh;
    if (n == 0) { wih = ego_wih_t; whh = ego_whh_t; bih = ego_bih; bhh = ego_bhh; }
    else        { wih = veh_wih_t; whh = veh_whh_t; bih = veh_bih; bhh = veh_bhh; }
    __shared__ float gs[16][G4];   // 32 KB gate exchange
    __shared__ float h2s[16][F];   // 8 KB new-h stash for pred head
    float acc[16];
    float bsum = bih[j] + bhh[j];
#pragma unroll
    for (int r = 0; r < 16; ++r) acc[r] = bsum;
    for (int k2 = 0; k2 < F; k2 += 4) {
        float wa0 = wih[(size_t)(k2    ) * G4 + j], wb0 = whh[(size_t)(k2    ) * G4 + j];
        float wa1 = wih[(size_t)(k2 + 1) * G4 + j], wb1 = whh[(size_t)(k2 + 1) * G4 + j];
        float wa2 = wih[(size_t)(k2 + 2) * G4 + j], wb2 = whh[(size_t)(k2 + 2) * G4 + j];
        float wa3 = wih[(size_t)(k2 + 3) * G4 + j], wb3 = whh[(size_t)(k2 + 3) * G4 + j];
#pragma unroll
        for (int r = 0; r < 16; ++r) {
            size_t bn = (size_t)(b0 + r) * N1 + n;
            float4 xv = *(const float4*)(xln  + bn * F + k2); // uniform -> s_load
            float4 hv = *(const float4*)(h_in + bn * F + k2); // uniform -> s_load
            acc[r] += xv.x * wa0 + xv.y * wa1 + xv.z * wa2 + xv.w * wa3
                    + hv.x * wb0 + hv.y * wb1 + hv.z * wb2 + hv.w * wb3;
        }
    }
#pragma unroll
    for (int r = 0; r < 16; ++r) gs[r][j] = acc[r];
    __syncthreads();
    for (int i = j; i < 16 * F; i += 512) {
        int r = i >> 7, f = i & 127;
        size_t bn = (size_t)(b0 + r) * N1 + n;
        float ig = gs[r][f], fg = gs[r][F + f], gg = gs[r][2 * F + f], og = gs[r][3 * F + f];
        float cold = c_in[bn * F + f];
        float c2 = sigmoidf(fg) * cold + sigmoidf(ig) * tanhf(gg);
        float h2 = sigmoidf(og) * tanhf(c2);
        c_out[bn * F + f] = c2;
        h_out[bn * F + f] = h2;
        h2s[r][f] = h2;
    }
    if (mode == 1) {
        const float* W  = (n == 0) ? out_ego_w : out_w;
        const float* bb = (n == 0) ? out_ego_b : out_b;
        __syncthreads();   // gate reads done before reusing gs
        for (int i = j; i < 16 * P6; i += 512) {
            int r = i / P6, jj = i % P6;
            float a = bb[jj];
            for (int k2 = 0; k2 < F; ++k2) a += h2s[r][k2] * W[k2 * P6 + jj];
            gs[r][jj] = a;
        }
        __syncthreads();
        if (j < 16 * NP) {
            int r = j / NP, p = j % NP;
            size_t bn = (size_t)(b0 + r) * N1 + n;
            float dl = gs[r][p * 6 + 0], yaw = gs[r][p * 6 + 1];
            float* pp = pred_pos + (bn * NP + p) * 2;
            float px = pp[0] + dl * cosf(yaw);
            float py = pp[1] + dl * sinf(yaw);
            pp[0] = px; pp[1] = py;
            float* y = out + (size_t)step * B * N1 * P6 + (bn * NP + p) * 6;
            y[0] = px; y[1] = py;
            y[2] = gs[r][p * 6 + 2]; y[3] = gs[r][p * 6 + 3];
            y[4] = gs[r][p * 6 + 4]; y[5] = gs[r][p * 6 + 5];
        }
    }
}

// ---------------- launcher ----------------
extern "C" void kernel_launch(void* const* d_in, const int* in_sizes, int n_in,
                              void* d_out, int out_size, void* d_ws, size_t ws_size,
                              hipStream_t stream) {
    const float* input      = (const float*)d_in[0];
    const float* init_pos   = (const float*)d_in[1];
    const float* lane_input = (const float*)d_in[2];
    const float* mask_input = (const float*)d_in[3];
    const float* lane_mask  = (const float*)d_in[4];
    const float* conv_w     = (const float*)d_in[5];
    const float* conv_b     = (const float*)d_in[6];
    const float* pos_w      = (const float*)d_in[7];
    const float* pos_b      = (const float*)d_in[8];
    const float* lane_w1    = (const float*)d_in[9];
    const float* lane_b1    = (const float*)d_in[10];
    const float* lane_w2    = (const float*)d_in[11];
    const float* lane_b2    = (const float*)d_in[12];
    const float* lane_to_f  = (const float*)d_in[13];
    const float* wq         = (const float*)d_in[14];
    const float* wk         = (const float*)d_in[15];
    const float* wv         = (const float*)d_in[16];
    const float* wo         = (const float*)d_in[17];
    const float* ln_ego_g   = (const float*)d_in[18];
    const float* ln_ego_b   = (const float*)d_in[19];
    const float* ln_g       = (const float*)d_in[20];
    const float* ln_b       = (const float*)d_in[21];
    const float* ego_wih    = (const float*)d_in[22];
    const float* ego_whh    = (const float*)d_in[23];
    const float* ego_bih    = (const float*)d_in[24];
    const float* ego_bhh    = (const float*)d_in[25];
    const float* veh_wih    = (const float*)d_in[26];
    const float* veh_whh    = (const float*)d_in[27];
    const float* veh_bih    = (const float*)d_in[28];
    const float* veh_bhh    = (const float*)d_in[29];
    const float* out_ego_w  = (const float*)d_in[30];
    const float* out_ego_b  = (const float*)d_in[31];
    const float* out_w      = (const float*)d_in[32];
    const float* out_b      = (const float*)d_in[33];

    float* out = (float*)d_out;
    float* ws = (float*)d_ws;

    // workspace layout (floats)
    float* kv       = ws;                        // B*KVN*F
    float* qb       = kv + (size_t)B * KVN * F;  // B*N1*F
    float* kb       = qb + (size_t)B * N1 * F;   // B*KVN*F
    float* vb       = kb + (size_t)B * KVN * F;  // B*KVN*F
    float* ao       = vb + (size_t)B * KVN * F;  // B*N1*F
    float* xln      = ao + (size_t)B * N1 * F;   // B*N1*F
    float* h0       = xln + (size_t)B * N1 * F;
    float* h1p      = h0 + (size_t)B * N1 * F;
    float* c0       = h1p + (size_t)B * N1 * F;
    float* c1p      = c0 + (size_t)B * N1 * F;
    float* hist_pos = c1p + (size_t)B * N1 * F;             // HH*B*N1*2
    float* pred_pos = hist_pos + (size_t)HH * B * N1 * 2;   // B*N1*NP*2
    float* wt       = pred_pos + (size_t)B * N1 * NP * 2;   // 4 * G4*F
    float* ego_wih_t = wt;
    float* ego_whh_t = wt + (size_t)G4 * F;
    float* veh_wih_t = wt + (size_t)2 * G4 * F;
    float* veh_whh_t = wt + (size_t)3 * G4 * F;

    float* hb[2] = {h0, h1p};
    float* cb[2] = {c0, c1p};

    // ---- init ----
    hipMemsetAsync(h0, 0, (size_t)B * N1 * F * sizeof(float), stream);
    hipMemsetAsync(c0, 0, (size_t)B * N1 * F * sizeof(float), stream);
    k_lane_tok<<<B * L, 64, 0, stream>>>(lane_input, lane_w1, lane_b1, lane_w2, lane_b2,
                                         lane_to_f, kv);
    k_hist_pos<<<(B * N1 + 255) / 256, 256, 0, stream>>>(input, init_pos, hist_pos, pred_pos);
    k_transpose_all<<<(4 * G4 * F + 255) / 256, 256, 0, stream>>>(ego_wih, ego_whh, veh_wih,
                                                                  veh_whh, wt);
    k_lane_kv<<<B * 8, 256, 0, stream>>>(kv, wk, wv, kb, vb);

    int cur = 0;
    // ---- history ----
    for (int t = 0; t < HH; ++t) {
        k_tok_qkv<<<B * 4, 256, 0, stream>>>(input, hist_pos, hb[cur], pred_pos,
                                             conv_w, conv_b, pos_w, pos_b,
                                             wq, wk, wv, kv, qb, kb, vb, 0, t);
        k_attn<<<B * 4, 64, 0, stream>>>(qb, kb, vb, mask_input, lane_mask, ao);
        k_proj_ln<<<B * 4, 256, 0, stream>>>(ao, kv, wo, ln_ego_g, ln_ego_b, ln_g, ln_b, xln);
        k_lstm_pred<<<N1 * 8, 512, 0, stream>>>(xln, ego_wih_t, ego_whh_t, ego_bih, ego_bhh,
                                                veh_wih_t, veh_whh_t, veh_bih, veh_bhh,
                                                hb[cur], cb[cur], hb[1 - cur], cb[1 - cur],
                                                out_ego_w, out_ego_b, out_w, out_b,
                                                pred_pos, out, 0, 0);
        cur ^= 1;
    }

    // ---- prediction ----
    for (int s = 0; s < LEN; ++s) {
        k_tok_qkv<<<B * 4, 256, 0, stream>>>(input, hist_pos, hb[cur], pred_pos,
                                             conv_w, conv_b, pos_w, pos_b,
                                             wq, wk, wv, kv, qb, kb, vb, 1, 0);
        k_attn<<<B * 4, 64, 0, stream>>>(qb, kb, vb, mask_input, lane_mask, ao);
        k_proj_ln<<<B * 4, 256, 0, stream>>>(ao, kv, wo, ln_ego_g, ln_ego_b, ln_g, ln_b, xln);
        k_lstm_pred<<<N1 * 8, 512, 0, stream>>>(xln, ego_wih_t, ego_whh_t, ego_bih, ego_bhh,
                                                veh_wih_t, veh_whh_t, veh_bih, veh_bhh,
                                                hb[cur], cb[cur], hb[1 - cur], cb[1 - cur],
                                                out_ego_w, out_ego_b, out_w, out_b,
                                                pred_pos, out, 1, s);
        cur ^= 1;
    }
}